// Round 11
// baseline (543.726 us; speedup 1.0000x reference)
//
#include <hip/hip_runtime.h>
#include <math.h>

#define NG 64          // graphs
#define F_IN 128
#define NEG_SLOPE 0.2f

typedef __attribute__((ext_vector_type(8))) short s16x8;
typedef __attribute__((ext_vector_type(4))) float f32x4;

// ---------- helpers ----------
static __device__ __forceinline__ float elu_f(float x) { return x > 0.f ? x : expm1f(x); }
static __device__ __forceinline__ float lrelu(float x) { return x > 0.f ? x : NEG_SLOPE * x; }
static __device__ __forceinline__ unsigned enc_f32(float x) {
    unsigned u = __float_as_uint(x);
    return (u & 0x80000000u) ? ~u : (u | 0x80000000u);
}
static __device__ __forceinline__ float dec_f32(unsigned u) {
    unsigned b = (u & 0x80000000u) ? (u & 0x7fffffffu) : ~u;
    return __uint_as_float(b);
}
static __device__ __forceinline__ unsigned short bf16_rn(float x) {
    unsigned u = __float_as_uint(x);
    unsigned r = u + 0x7FFFu + ((u >> 16) & 1u);
    return (unsigned short)(r >> 16);
}
static __device__ __forceinline__ float bf16_to_f32(unsigned short h) {
    return __uint_as_float(((unsigned)h) << 16);
}

// MFMA fragment-order layout: element (row,k) of a [R][K] bf16 matrix.
static __device__ __forceinline__ size_t fragaddr(int row, int k, int K) {
    return ((size_t)(row >> 4) * (K >> 5) + (k >> 5)) * 512
         + (size_t)(((k & 31) >> 3) * 128 + (row & 15) * 8 + (k & 7));
}

static __device__ __forceinline__ void frag_store8(const float* v, unsigned short* hi,
                                                   unsigned short* lo, int row, int k0, int K) {
    unsigned short h[8], l[8];
    #pragma unroll
    for (int i = 0; i < 8; ++i) {
        h[i] = bf16_rn(v[i]);
        l[i] = bf16_rn(v[i] - bf16_to_f32(h[i]));
    }
    size_t a = fragaddr(row, k0, K);
    *(ushort4*)&hi[a]     = make_ushort4(h[0], h[1], h[2], h[3]);
    *(ushort4*)&hi[a + 4] = make_ushort4(h[4], h[5], h[6], h[7]);
    *(ushort4*)&lo[a]     = make_ushort4(l[0], l[1], l[2], l[3]);
    *(ushort4*)&lo[a + 4] = make_ushort4(l[4], l[5], l[6], l[7]);
}

// ---------- pre-pack: f32 [R][K] -> frag-order hi/lo bf16 ----------
__global__ void convert_frag(const float* __restrict__ in, unsigned short* __restrict__ hi,
                             unsigned short* __restrict__ lo, int R, int K) {
    int t = blockIdx.x * blockDim.x + threadIdx.x;
    if (t * 8 >= R * K) return;
    int row = (t * 8) / K;
    int k0 = (t * 8) % K;
    float4 v0 = *(const float4*)&in[(size_t)row * K + k0];
    float4 v1 = *(const float4*)&in[(size_t)row * K + k0 + 4];
    float v[8] = {v0.x, v0.y, v0.z, v0.w, v1.x, v1.y, v1.z, v1.w};
    frag_store8(v, hi, lo, row, k0, K);
}

// all 4 weight matrices in one launch (52 blocks)
__global__ void convert_weights(const float* __restrict__ We, const float* __restrict__ W1,
                                const float* __restrict__ W2, const float* __restrict__ W3,
                                unsigned short* WhE, unsigned short* WlE,
                                unsigned short* Wh1, unsigned short* Wl1,
                                unsigned short* Wh2, unsigned short* Wl2,
                                unsigned short* Wh3, unsigned short* Wl3) {
    int b = blockIdx.x;
    const float* in; unsigned short* hi; unsigned short* lo; int R, K, base;
    if (b < 4)       { in = We; hi = WhE; lo = WlE; R = 64;  K = 128; base = 0; }
    else if (b < 12) { in = W1; hi = Wh1; lo = Wl1; R = 256; K = 64;  base = 4; }
    else if (b < 44) { in = W2; hi = Wh2; lo = Wl2; R = 256; K = 256; base = 12; }
    else             { in = W3; hi = Wh3; lo = Wl3; R = 64;  K = 256; base = 44; }
    int t = (b - base) * 256 + threadIdx.x;
    if (t * 8 >= R * K) return;
    int row = (t * 8) / K;
    int k0 = (t * 8) % K;
    float4 v0 = *(const float4*)&in[(size_t)row * K + k0];
    float4 v1 = *(const float4*)&in[(size_t)row * K + k0 + 4];
    float v[8] = {v0.x, v0.y, v0.z, v0.w, v1.x, v1.y, v1.z, v1.w};
    frag_store8(v, hi, lo, row, k0, K);
}

// u[h][i] = sum_o W1[h*64+o][i] * a[h][o]   (layer-1 commute attention scalars)
__global__ void uvec_kernel(const float* __restrict__ W1, const float* __restrict__ a1s,
                            const float* __restrict__ a1d,
                            float* __restrict__ us, float* __restrict__ ud) {
    int h = threadIdx.x >> 6;
    int i = threadIdx.x & 63;
    float s = 0.f, d = 0.f;
    for (int o = 0; o < 64; ++o) {
        float w = W1[(h * 64 + o) * 64 + i];
        s = fmaf(w, a1s[h * 64 + o], s);
        d = fmaf(w, a1d[h * 64 + o], d);
    }
    us[h * 64 + i] = s;
    ud[h * 64 + i] = d;
}

// ---------- CSR build ----------
__global__ void hist_kernel(const int* __restrict__ ei, int* __restrict__ cnt, int E, int N) {
    int e = blockIdx.x * blockDim.x + threadIdx.x;
    int ET = E + N;
    if (e >= ET) return;
    int dst = (e < E) ? ei[E + e] : (e - E);
    atomicAdd(&cnt[dst], 1);
}

__global__ void scan1_kernel(const int* __restrict__ cnt, int* __restrict__ excl,
                             int* __restrict__ bsum, int n) {
    __shared__ int sm[256];
    int t = threadIdx.x;
    int base = blockIdx.x * 1024 + t * 4;
    int v[4];
    #pragma unroll
    for (int u = 0; u < 4; ++u) { int idx = base + u; v[u] = (idx < n) ? cnt[idx] : 0; }
    int tsum = v[0] + v[1] + v[2] + v[3];
    sm[t] = tsum;
    __syncthreads();
    for (int off = 1; off < 256; off <<= 1) {
        int y = (t >= off) ? sm[t - off] : 0;
        __syncthreads();
        sm[t] += y;
        __syncthreads();
    }
    int run = sm[t] - tsum;
    #pragma unroll
    for (int u = 0; u < 4; ++u) {
        int idx = base + u;
        if (idx < n) excl[idx] = run;
        run += v[u];
    }
    if (t == 255) bsum[blockIdx.x] = sm[255];
}

__global__ void scan2_kernel(int* __restrict__ bsum, int* __restrict__ offs, int nb, int n) {
    if (blockIdx.x == 0 && threadIdx.x == 0) {
        int run = 0;
        for (int b = 0; b < nb; ++b) { int t = bsum[b]; bsum[b] = run; run += t; }
        offs[n] = run;
    }
}

// adds block offsets AND initializes the scatter cursor (saves a memset+pass)
__global__ void scan3_kernel(int* __restrict__ offs, const int* __restrict__ bsum,
                             int* __restrict__ cur, int n) {
    int base = blockIdx.x * 1024 + threadIdx.x * 4;
    int add = bsum[blockIdx.x];
    #pragma unroll
    for (int u = 0; u < 4; ++u) {
        int idx = base + u;
        if (idx < n) { int v = offs[idx] + add; offs[idx] = v; cur[idx] = v; }
    }
}

__global__ void scatter_kernel(const int* __restrict__ ei, int* __restrict__ cur,
                               int* __restrict__ csr_src, int E, int N) {
    int e = blockIdx.x * blockDim.x + threadIdx.x;
    int ET = E + N;
    if (e >= ET) return;
    int src, dst;
    if (e < E) { src = ei[e]; dst = ei[E + e]; }
    else       { src = e - E; dst = e - E; }
    int pos = atomicAdd(&cur[dst], 1);
    csr_src[pos] = src;
}

// ---------- frag-order LDS-free split-bf16 MFMA GEMM ----------
// OUTM: 0=f32 row-major, 1=bf16 row-major, 3=frag-order split (Ohi/Olo).
template<int K, int AK, int BN, int HATT, bool SHARED, bool SLICED, bool DO_ELU, int OUTM>
__global__ __launch_bounds__(256) void gemm_frag(const unsigned short* __restrict__ Ahi,
                                                 const unsigned short* __restrict__ Alo,
                                                 const unsigned short* __restrict__ Whi,
                                                 const unsigned short* __restrict__ Wlo,
                                                 void* __restrict__ OutV,
                                                 unsigned short* __restrict__ Ohi,
                                                 unsigned short* __restrict__ Olo,
                                                 int M,
                                                 const float* __restrict__ bias,
                                                 const float* __restrict__ asrc,
                                                 const float* __restrict__ adst,
                                                 float* __restrict__ S, float* __restrict__ D,
                                                 int N) {
    constexpr int RF = (BN == 256) ? 4 : 2;
    const int t = threadIdx.x;
    const int lane = t & 63;
    const int w = t >> 6;
    const int lj = lane & 15;
    const int kg = lane >> 4;
    const int n0 = blockIdx.x * ((BN == 256) ? 64 : 128);
    const int m0 = blockIdx.y * BN;
    const int rbase = (BN == 256) ? 0 : w * 32;
    const int cbase = (BN == 256) ? w * 64 : 0;
    const int aoff = SLICED ? blockIdx.y * K : 0;
    const unsigned short* __restrict__ WhiB = SLICED ? Whi + (size_t)blockIdx.y * BN * K : Whi;
    const unsigned short* __restrict__ WloB = SLICED ? Wlo + (size_t)blockIdx.y * BN * K : Wlo;

    f32x4 acc[RF][4];
    #pragma unroll
    for (int rf = 0; rf < RF; ++rf)
        #pragma unroll
        for (int cf = 0; cf < 4; ++cf) acc[rf][cf] = (f32x4){0.f, 0.f, 0.f, 0.f};

    for (int kc = 0; kc < K; kc += 32) {
        s16x8 ah[RF], al[RF];
        #pragma unroll
        for (int rf = 0; rf < RF; ++rf) {
            size_t a = fragaddr(n0 + rbase + rf * 16 + lj, aoff + kc + kg * 8, AK);
            ah[rf] = *(const s16x8*)&Ahi[a];
            al[rf] = *(const s16x8*)&Alo[a];
        }
        #pragma unroll
        for (int cf = 0; cf < 4; ++cf) {
            int bcol = (SLICED ? 0 : m0) + cbase + cf * 16 + lj;
            size_t b = fragaddr(bcol, kc + kg * 8, K);
            s16x8 bh = *(const s16x8*)&WhiB[b];
            s16x8 bl = *(const s16x8*)&WloB[b];
            #pragma unroll
            for (int rf = 0; rf < RF; ++rf) {
                acc[rf][cf] = __builtin_amdgcn_mfma_f32_16x16x32_bf16(ah[rf], bh, acc[rf][cf], 0, 0, 0);
                acc[rf][cf] = __builtin_amdgcn_mfma_f32_16x16x32_bf16(ah[rf], bl, acc[rf][cf], 0, 0, 0);
                acc[rf][cf] = __builtin_amdgcn_mfma_f32_16x16x32_bf16(al[rf], bh, acc[rf][cf], 0, 0, 0);
            }
        }
    }

    #pragma unroll
    for (int cf = 0; cf < 4; ++cf) {
        int gcol = m0 + cbase + cf * 16 + lj;
        float bv = bias ? bias[gcol] : 0.f;
        #pragma unroll
        for (int rf = 0; rf < RF; ++rf) {
            #pragma unroll
            for (int r = 0; r < 4; ++r) {
                int gn = n0 + rbase + rf * 16 + (lane >> 4) * 4 + r;
                if (gn < N) {
                    float o = acc[rf][cf][r] + bv;
                    if (DO_ELU) o = elu_f(o);
                    if (OUTM == 0) {
                        ((float*)OutV)[(size_t)gn * M + gcol] = o;
                    } else if (OUTM == 1) {
                        ((unsigned short*)OutV)[(size_t)gn * M + gcol] = bf16_rn(o);
                    } else {
                        unsigned short hv = bf16_rn(o);
                        unsigned short lv = bf16_rn(o - bf16_to_f32(hv));
                        size_t a2 = fragaddr(gn, gcol, M);
                        Ohi[a2] = hv; Olo[a2] = lv;
                    }
                }
            }
        }
    }
    if (HATT > 0) {
        const int HS = SHARED ? HATT : 1;
        #pragma unroll
        for (int hh = 0; hh < HS; ++hh) {
            const int head = SHARED ? hh : w;
            float aw[4], dw[4], bw[4];
            #pragma unroll
            for (int c2 = 0; c2 < 4; ++c2) {
                aw[c2] = asrc[head * 64 + c2 * 16 + lj];
                dw[c2] = adst[head * 64 + c2 * 16 + lj];
                bw[c2] = bias ? bias[m0 + cbase + c2 * 16 + lj] : 0.f;
            }
            #pragma unroll
            for (int rf = 0; rf < RF; ++rf) {
                #pragma unroll
                for (int r = 0; r < 4; ++r) {
                    float sp = 0.f, dp = 0.f;
                    #pragma unroll
                    for (int c2 = 0; c2 < 4; ++c2) {
                        float vv = acc[rf][c2][r] + bw[c2];
                        sp = fmaf(vv, aw[c2], sp);
                        dp = fmaf(vv, dw[c2], dp);
                    }
                    #pragma unroll
                    for (int off = 1; off < 16; off <<= 1) {
                        sp += __shfl_xor(sp, off);
                        dp += __shfl_xor(dp, off);
                    }
                    if (lj == 0) {
                        int gn = n0 + rbase + rf * 16 + (lane >> 4) * 4 + r;
                        if (gn < N) { S[gn * HATT + head] = sp; D[gn * HATT + head] = dp; }
                    }
                }
            }
        }
    }
}

// ---------- layer-1 aggregation over bf16 emb (commuted); outputs frag-order split ----------
__global__ __launch_bounds__(256, 8) void gat_agg_x(const unsigned short* __restrict__ xb, // [N][64] bf16
                                                    const float* __restrict__ s,   // [N][4]
                                                    const float* __restrict__ d,
                                                    const int* __restrict__ offs,
                                                    const int* __restrict__ csr_src,
                                                    unsigned short* __restrict__ Gh,
                                                    unsigned short* __restrict__ Gl,
                                                    int N) {
    __shared__ float stash[4][64 * 5];
    int wv = threadIdx.x >> 6;
    int lane = threadIdx.x & 63;
    int node = (blockIdx.x * blockDim.x + threadIdx.x) >> 6;
    if (node >= N) return;
    float* st = stash[wv];
    int e0 = offs[node], e1 = offs[node + 1];
    float4 dv4 = *(const float4*)&d[node * 4];
    float dd[4] = {dv4.x, dv4.y, dv4.z, dv4.w};
    float mrun[4] = {-INFINITY, -INFINITY, -INFINITY, -INFINITY};
    float den[4] = {0.f, 0.f, 0.f, 0.f};
    float acc[4] = {0.f, 0.f, 0.f, 0.f};

    for (int base = e0; base < e1; base += 64) {
        int cnt = min(64, e1 - base);
        float ev[4] = {-INFINITY, -INFINITY, -INFINITY, -INFINITY};
        if (lane < cnt) {
            int src = csr_src[base + lane];
            float4 sv = *(const float4*)&s[src * 4];
            ev[0] = lrelu(sv.x + dd[0]); ev[1] = lrelu(sv.y + dd[1]);
            ev[2] = lrelu(sv.z + dd[2]); ev[3] = lrelu(sv.w + dd[3]);
            st[lane * 5 + 0] = ev[0]; st[lane * 5 + 1] = ev[1];
            st[lane * 5 + 2] = ev[2]; st[lane * 5 + 3] = ev[3];
            st[lane * 5 + 4] = __int_as_float(src);
        }
        #pragma unroll
        for (int h = 0; h < 4; ++h) {
            float m = ev[h];
            #pragma unroll
            for (int off = 32; off; off >>= 1) m = fmaxf(m, __shfl_xor(m, off));
            float mnew = fmaxf(mrun[h], m);
            float scale = __expf(mrun[h] - mnew);
            acc[h] *= scale; den[h] *= scale;
            mrun[h] = mnew;
        }
        int k = 0;
        for (; k + 4 <= cnt; k += 4) {
            int si[4];
            #pragma unroll
            for (int u = 0; u < 4; ++u) si[u] = __float_as_int(st[(k + u) * 5 + 4]);
            float vx[4];
            #pragma unroll
            for (int u = 0; u < 4; ++u) vx[u] = bf16_to_f32(xb[(size_t)si[u] * 64 + lane]);
            #pragma unroll
            for (int u = 0; u < 4; ++u) {
                #pragma unroll
                for (int h = 0; h < 4; ++h) {
                    float p = __expf(st[(k + u) * 5 + h] - mrun[h]);
                    den[h] += p;
                    acc[h] = fmaf(p, vx[u], acc[h]);
                }
            }
        }
        for (; k < cnt; ++k) {
            int src = __float_as_int(st[k * 5 + 4]);
            float v = bf16_to_f32(xb[(size_t)src * 64 + lane]);
            #pragma unroll
            for (int h = 0; h < 4; ++h) {
                float p = __expf(st[k * 5 + h] - mrun[h]);
                den[h] += p;
                acc[h] = fmaf(p, v, acc[h]);
            }
        }
    }
    #pragma unroll
    for (int h = 0; h < 4; ++h) {
        float v = acc[h] / (den[h] + 1e-16f);
        unsigned short hv = bf16_rn(v);
        unsigned short lv = bf16_rn(v - bf16_to_f32(hv));
        size_t a = fragaddr(node, h * 64 + lane, 256);
        Gh[a] = hv; Gl[a] = lv;
    }
}

// ---------- layer-2 aggregation: TWO waves per node (2 heads / 128 ch each) ----------
template<bool FRAGOUT>
__global__ __launch_bounds__(256, 8) void gat_agg2(const unsigned short* __restrict__ hp,
                                                   const float* __restrict__ s,   // [N][4]
                                                   const float* __restrict__ d,
                                                   const int* __restrict__ offs,
                                                   const int* __restrict__ csr_src,
                                                   const float* __restrict__ bias,
                                                   float* __restrict__ outF,
                                                   unsigned short* __restrict__ outHi,
                                                   unsigned short* __restrict__ outLo,
                                                   int N) {
    __shared__ float stash[4][64 * 3];
    int wv = threadIdx.x >> 6;
    int lane = threadIdx.x & 63;
    int gw = (blockIdx.x * blockDim.x + threadIdx.x) >> 6;
    int node = gw >> 1;
    int half = gw & 1;
    if (node >= N) return;
    float* st = stash[wv];
    int e0 = offs[node], e1 = offs[node + 1];
    const int h0 = half * 2;
    float2 dv = *(const float2*)&d[node * 4 + h0];
    const float dd0 = dv.x, dd1 = dv.y;
    const int hh = lane >> 5;             // head within pair
    const int ci = (lane & 31) * 2;       // channel pair within head
    const int rowoff = (h0 + hh) * 64 + ci;

    float mrun = -INFINITY;
    float a0 = 0.f, a1 = 0.f, den = 0.f;

    for (int base = e0; base < e1; base += 64) {
        int cnt = min(64, e1 - base);
        float ev0 = -INFINITY, ev1 = -INFINITY;
        if (lane < cnt) {
            int src = csr_src[base + lane];
            float2 sv = *(const float2*)&s[src * 4 + h0];
            ev0 = lrelu(sv.x + dd0);
            ev1 = lrelu(sv.y + dd1);
            st[lane * 3 + 0] = ev0;
            st[lane * 3 + 1] = ev1;
            st[lane * 3 + 2] = __int_as_float(src);
        }
        float m0 = ev0, m1 = ev1;
        #pragma unroll
        for (int off = 32; off; off >>= 1) {
            m0 = fmaxf(m0, __shfl_xor(m0, off));
            m1 = fmaxf(m1, __shfl_xor(m1, off));
        }
        float mch = hh ? m1 : m0;
        float mnew = fmaxf(mrun, mch);
        float scale = __expf(mrun - mnew);
        a0 *= scale; a1 *= scale; den *= scale;
        mrun = mnew;

        int k = 0;
        for (; k + 4 <= cnt; k += 4) {
            float ea = st[(k + 0) * 3 + hh];
            float eb = st[(k + 1) * 3 + hh];
            float ec = st[(k + 2) * 3 + hh];
            float ed = st[(k + 3) * 3 + hh];
            int sa = __float_as_int(st[(k + 0) * 3 + 2]);
            int sb = __float_as_int(st[(k + 1) * 3 + 2]);
            int sc = __float_as_int(st[(k + 2) * 3 + 2]);
            int sd_ = __float_as_int(st[(k + 3) * 3 + 2]);
            float pa = __expf(ea - mrun);
            float pb = __expf(eb - mrun);
            float pc = __expf(ec - mrun);
            float pd = __expf(ed - mrun);
            den += (pa + pb) + (pc + pd);
            unsigned ua = *(const unsigned*)&hp[(size_t)sa * 256 + rowoff];
            unsigned ub = *(const unsigned*)&hp[(size_t)sb * 256 + rowoff];
            unsigned uc = *(const unsigned*)&hp[(size_t)sc * 256 + rowoff];
            unsigned ud = *(const unsigned*)&hp[(size_t)sd_ * 256 + rowoff];
            a0 = fmaf(pa, __uint_as_float((ua & 0xffffu) << 16), a0);
            a1 = fmaf(pa, __uint_as_float(ua & 0xffff0000u), a1);
            a0 = fmaf(pb, __uint_as_float((ub & 0xffffu) << 16), a0);
            a1 = fmaf(pb, __uint_as_float(ub & 0xffff0000u), a1);
            a0 = fmaf(pc, __uint_as_float((uc & 0xffffu) << 16), a0);
            a1 = fmaf(pc, __uint_as_float(uc & 0xffff0000u), a1);
            a0 = fmaf(pd, __uint_as_float((ud & 0xffffu) << 16), a0);
            a1 = fmaf(pd, __uint_as_float(ud & 0xffff0000u), a1);
        }
        for (; k < cnt; ++k) {
            float e = st[k * 3 + hh];
            int src = __float_as_int(st[k * 3 + 2]);
            float p = __expf(e - mrun);
            den += p;
            unsigned uv = *(const unsigned*)&hp[(size_t)src * 256 + rowoff];
            a0 = fmaf(p, __uint_as_float((uv & 0xffffu) << 16), a0);
            a1 = fmaf(p, __uint_as_float(uv & 0xffff0000u), a1);
        }
    }

    float inv = 1.0f / (den + 1e-16f);
    float2 bv = *(const float2*)&bias[rowoff];
    float o0 = elu_f(a0 * inv + bv.x);
    float o1 = elu_f(a1 * inv + bv.y);
    if (FRAGOUT) {
        unsigned short hv0 = bf16_rn(o0), hv1 = bf16_rn(o1);
        unsigned short lv0 = bf16_rn(o0 - bf16_to_f32(hv0));
        unsigned short lv1 = bf16_rn(o1 - bf16_to_f32(hv1));
        size_t a = fragaddr(node, rowoff, 256);
        *(ushort2*)&outHi[a] = make_ushort2(hv0, hv1);
        *(ushort2*)&outLo[a] = make_ushort2(lv0, lv1);
    } else {
        *(float2*)&outF[(size_t)node * 256 + rowoff] = make_float2(o0, o1);
    }
}

// ---------- layer-3 aggregation (H=1): one wave per node, bf16 table, f32 out ----------
__global__ __launch_bounds__(256, 8) void gat_agg1(const unsigned short* __restrict__ hp,
                                                   const float* __restrict__ s,
                                                   const float* __restrict__ d,
                                                   const int* __restrict__ offs,
                                                   const int* __restrict__ csr_src,
                                                   const float* __restrict__ bias,
                                                   float* __restrict__ outF, int N) {
    __shared__ float stash[4][64 * 2];
    int wv = threadIdx.x >> 6;
    int lane = threadIdx.x & 63;
    int node = (blockIdx.x * blockDim.x + threadIdx.x) >> 6;
    if (node >= N) return;
    float* st = stash[wv];
    int e0 = offs[node], e1 = offs[node + 1];
    float dd = d[node];

    float mrun = -INFINITY;
    float acc0 = 0.f, den = 0.f;

    for (int base = e0; base < e1; base += 64) {
        int cnt = min(64, e1 - base);
        float ev = -INFINITY;
        if (lane < cnt) {
            int src = csr_src[base + lane];
            ev = lrelu(s[src] + dd);
            st[lane * 2 + 0] = ev;
            st[lane * 2 + 1] = __int_as_float(src);
        }
        float m = ev;
        #pragma unroll
        for (int off = 32; off; off >>= 1) m = fmaxf(m, __shfl_xor(m, off));
        float mnew = fmaxf(mrun, m);
        float scale = __expf(mrun - mnew);
        acc0 *= scale; den *= scale;
        mrun = mnew;

        int k = 0;
        for (; k + 4 <= cnt; k += 4) {
            float ea = st[(k + 0) * 2];
            float eb = st[(k + 1) * 2];
            float ec = st[(k + 2) * 2];
            float ed = st[(k + 3) * 2];
            int sa = __float_as_int(st[(k + 0) * 2 + 1]);
            int sb = __float_as_int(st[(k + 1) * 2 + 1]);
            int sc = __float_as_int(st[(k + 2) * 2 + 1]);
            int sd_ = __float_as_int(st[(k + 3) * 2 + 1]);
            float pa = __expf(ea - mrun);
            float pb = __expf(eb - mrun);
            float pc = __expf(ec - mrun);
            float pd = __expf(ed - mrun);
            den += (pa + pb) + (pc + pd);
            float ha = bf16_to_f32(hp[(size_t)sa * 64 + lane]);
            float hb = bf16_to_f32(hp[(size_t)sb * 64 + lane]);
            float hc = bf16_to_f32(hp[(size_t)sc * 64 + lane]);
            float hdv = bf16_to_f32(hp[(size_t)sd_ * 64 + lane]);
            acc0 = fmaf(pa, ha, acc0);
            acc0 = fmaf(pb, hb, acc0);
            acc0 = fmaf(pc, hc, acc0);
            acc0 = fmaf(pd, hdv, acc0);
        }
        for (; k < cnt; ++k) {
            float e = st[k * 2];
            int src = __float_as_int(st[k * 2 + 1]);
            float p = __expf(e - mrun);
            den += p;
            acc0 = fmaf(p, bf16_to_f32(hp[(size_t)src * 64 + lane]), acc0);
        }
    }
    float inv = 1.0f / (den + 1e-16f);
    outF[(size_t)node * 64 + lane] = elu_f(acc0 * inv + bias[lane]);
}

// ---------- pooling ----------
__global__ void pool_init(float* gsum, unsigned* gmax, int* gcnt) {
    int t = blockIdx.x * blockDim.x + threadIdx.x;
    if (t < NG * 64) { gsum[t] = 0.f; gmax[t] = enc_f32(-INFINITY); }
    if (t < NG) gcnt[t] = 0;
}

__global__ void pool_reduce(const float* __restrict__ h3, const int* __restrict__ batch,
                            float* __restrict__ gsum, unsigned* __restrict__ gmax,
                            int* __restrict__ gcnt, int N, int per) {
    int w = (blockIdx.x * blockDim.x + threadIdx.x) >> 6;
    int lane = threadIdx.x & 63;
    int n0 = w * per;
    int n1 = min(N, n0 + per);
    float lsum = 0.f, lmax = -INFINITY;
    int cur = -1, cnt = 0;
    for (int n = n0; n < n1; ++n) {
        int g = batch[n];
        if (g != cur) {
            if (cur >= 0) {
                atomicAdd(&gsum[cur * 64 + lane], lsum);
                atomicMax(&gmax[cur * 64 + lane], enc_f32(lmax));
                if (lane == 0) atomicAdd(&gcnt[cur], cnt);
            }
            cur = g; lsum = 0.f; lmax = -INFINITY; cnt = 0;
        }
        float v = h3[(size_t)n * 64 + lane];
        lsum += v; lmax = fmaxf(lmax, v); cnt++;
    }
    if (cur >= 0) {
        atomicAdd(&gsum[cur * 64 + lane], lsum);
        atomicMax(&gmax[cur * 64 + lane], enc_f32(lmax));
        if (lane == 0) atomicAdd(&gcnt[cur], cnt);
    }
}

// ---------- classifier: one block per graph ----------
__global__ __launch_bounds__(128) void classifier(const float* __restrict__ gsum,
                                                  const unsigned* __restrict__ gmax,
                                                  const int* __restrict__ gcnt,
                                                  const float* __restrict__ Wc1,
                                                  const float* __restrict__ bc1,
                                                  const float* __restrict__ Wc2,
                                                  const float* __restrict__ bc2,
                                                  float* __restrict__ out) {
    __shared__ float gv[128];
    __shared__ float z1[64];
    int g = blockIdx.x, t = threadIdx.x;
    int cnt = gcnt[g];
    if (t < 64) {
        gv[t] = gsum[g * 64 + t] / fmaxf((float)cnt, 1.f);
    } else {
        float mx = dec_f32(gmax[g * 64 + (t - 64)]);
        gv[t] = (cnt > 0) ? mx : 0.f;
    }
    __syncthreads();
    if (t < 64) {
        float a = bc1[t];
        for (int k = 0; k < 128; ++k) a = fmaf(Wc1[t * 128 + k], gv[k], a);
        z1[t] = a > 0.f ? a : 0.f;
    }
    __syncthreads();
    if (t < 10) {
        float a = bc2[t];
        for (int k = 0; k < 64; ++k) a = fmaf(Wc2[t * 64 + k], z1[k], a);
        out[g * 10 + t] = a;
    }
}

// ---------- launch ----------
extern "C" void kernel_launch(void* const* d_in, const int* in_sizes, int n_in,
                              void* d_out, int out_size, void* d_ws, size_t ws_size,
                              hipStream_t stream) {
    const float* x      = (const float*)d_in[0];
    const int*   ei     = (const int*)d_in[1];
    const int*   batch  = (const int*)d_in[2];
    const float* W_emb  = (const float*)d_in[3];
    const float* b_emb  = (const float*)d_in[4];
    const float* W1     = (const float*)d_in[5];
    const float* as1    = (const float*)d_in[6];
    const float* ad1    = (const float*)d_in[7];
    const float* b1     = (const float*)d_in[8];
    const float* W2     = (const float*)d_in[9];
    const float* as2    = (const float*)d_in[10];
    const float* ad2    = (const float*)d_in[11];
    const float* b2     = (const float*)d_in[12];
    const float* W3     = (const float*)d_in[13];
    const float* as3    = (const float*)d_in[14];
    const float* ad3    = (const float*)d_in[15];
    const float* b3     = (const float*)d_in[16];
    const float* Wc1    = (const float*)d_in[17];
    const float* bc1    = (const float*)d_in[18];
    const float* Wc2    = (const float*)d_in[19];
    const float* bc2    = (const float*)d_in[20];

    const int N = in_sizes[0] / F_IN;   // 50000
    const int E = in_sizes[1] / 2;      // 800000
    const int ET = E + N;
    const int GB64 = (N + 63) / 64;     // BN=256 gemm, 64-row blocks
    const int GB128 = (N + 127) / 128;  // BN=64 gemms, 128-row blocks
    const int ROWS_FR = ((N + 255) / 256) * 256;
    const size_t FR128 = (size_t)(ROWS_FR / 16) * (128 / 32) * 512;
    const size_t FR256 = (size_t)(ROWS_FR / 16) * (256 / 32) * 512;

    size_t off = 0;
    auto alloc = [&](size_t bytes) -> void* {
        void* p = (char*)d_ws + off;
        off += (bytes + 255) & ~(size_t)255;
        return p;
    };
    unsigned short* Xh  = (unsigned short*)alloc(FR128 * 2);
    unsigned short* Xl  = (unsigned short*)alloc(FR128 * 2);
    unsigned short* Aemb= (unsigned short*)alloc((size_t)N * 64 * 2);  // emb bf16; later H3b bf16
    unsigned short* Gh  = (unsigned short*)alloc(FR256 * 2);    // G frag; later C2 frag
    unsigned short* Gl  = (unsigned short*)alloc(FR256 * 2);
    unsigned short* C1h = (unsigned short*)alloc(FR256 * 2);
    unsigned short* C1l = (unsigned short*)alloc(FR256 * 2);
    unsigned short* H2b = (unsigned short*)alloc((size_t)N * 256 * 2); // h2 bf16; later h3 f32
    unsigned short* WhE = (unsigned short*)alloc(64 * 128 * 2);
    unsigned short* WlE = (unsigned short*)alloc(64 * 128 * 2);
    unsigned short* Wh1 = (unsigned short*)alloc(256 * 64 * 2);
    unsigned short* Wl1 = (unsigned short*)alloc(256 * 64 * 2);
    unsigned short* Wh2 = (unsigned short*)alloc(256 * 256 * 2);
    unsigned short* Wl2 = (unsigned short*)alloc(256 * 256 * 2);
    unsigned short* Wh3 = (unsigned short*)alloc(64 * 256 * 2);
    unsigned short* Wl3 = (unsigned short*)alloc(64 * 256 * 2);
    float*    us1     = (float*)alloc(4 * 64 * 4);
    float*    ud1     = (float*)alloc(4 * 64 * 4);
    float*    S       = (float*)alloc((size_t)N * 4 * 4);
    float*    D       = (float*)alloc((size_t)N * 4 * 4);
    int*      offs    = (int*)alloc((size_t)(N + 1) * 4);
    int*      cnt     = (int*)alloc((size_t)N * 4);
    int*      bsum    = (int*)alloc(64 * 4);
    int*      csr_src = (int*)alloc((size_t)ET * 4);
    float*    gsum    = (float*)alloc(NG * 64 * 4);
    unsigned* gmax    = (unsigned*)alloc(NG * 64 * 4);
    int*      gcnt    = (int*)alloc(NG * 4);
    (void)ws_size; (void)n_in; (void)out_size;

    const int SCB = (N + 1023) / 1024;

    // pre-pack to fragment order
    convert_frag<<<(N * 128 / 8 + 255) / 256, 256, 0, stream>>>(x, Xh, Xl, N, 128);
    convert_weights<<<52, 256, 0, stream>>>(W_emb, W1, W2, W3, WhE, WlE, Wh1, Wl1,
                                            Wh2, Wl2, Wh3, Wl3);
    uvec_kernel<<<1, 256, 0, stream>>>(W1, as1, ad1, us1, ud1);

    // CSR build
    hipMemsetAsync(cnt, 0, (size_t)N * 4, stream);
    hist_kernel<<<(ET + 255) / 256, 256, 0, stream>>>(ei, cnt, E, N);
    scan1_kernel<<<SCB, 256, 0, stream>>>(cnt, offs, bsum, N);
    scan2_kernel<<<1, 64, 0, stream>>>(bsum, offs, SCB, N);
    scan3_kernel<<<SCB, 256, 0, stream>>>(offs, bsum, cnt, N);
    scatter_kernel<<<(ET + 255) / 256, 256, 0, stream>>>(ei, cnt, csr_src, E, N);

    const int NWV = (N * 64 + 255) / 256;          // 1 wave/node
    const int NWV2 = (N * 128 + 255) / 256;        // 2 waves/node

    // embedding: Aemb(bf16) = x@W_embT + b_emb, fused s1,d1 via commute u-vectors
    gemm_frag<128, 128, 64, 4, true, false, false, 1><<<dim3(GB128, 1), 256, 0, stream>>>(
        Xh, Xl, WhE, WlE, Aemb, nullptr, nullptr, 64, b_emb, us1, ud1, S, D, N);
    // layer-1 commuted aggregation (gathers bf16 emb; outputs frag G)
    gat_agg_x<<<NWV, 256, 0, stream>>>(Aemb, S, D, offs, csr_src, Gh, Gl, N);
    // per-head transform: C1 = frag(elu(G_h @ W1_hT + b1))
    gemm_frag<64, 256, 64, 0, false, true, true, 3><<<dim3(GB128, 4), 256, 0, stream>>>(
        Gh, Gl, Wh1, Wl1, nullptr, C1h, C1l, 256, b1, nullptr, nullptr, nullptr, nullptr, N);
    // layer 2: H2b(bf16) = C1@W2T, fused s2,d2
    gemm_frag<256, 256, 256, 4, false, false, false, 1><<<dim3(GB64, 1), 256, 0, stream>>>(
        C1h, C1l, Wh2, Wl2, H2b, nullptr, nullptr, 256, nullptr, as2, ad2, S, D, N);
    // layer-2 aggregation: 2 waves/node, frag-order output
    gat_agg2<true><<<NWV2, 256, 0, stream>>>(H2b, S, D, offs, csr_src, b2,
                                             nullptr, Gh, Gl, N);
    // layer 3: H3b(bf16, in Aemb buffer) = C2@W3T, fused s3,d3
    gemm_frag<256, 256, 64, 1, true, false, false, 1><<<dim3(GB128, 1), 256, 0, stream>>>(
        Gh, Gl, Wh3, Wl3, Aemb, nullptr, nullptr, 64, nullptr, as3, ad3, S, D, N);
    gat_agg1<<<NWV, 256, 0, stream>>>(Aemb, S, D, offs, csr_src, b3, (float*)H2b, N);

    // pooling + classifier (h3 f32 in H2b buffer)
    pool_init<<<16, 256, 0, stream>>>(gsum, gmax, gcnt);
    const int PBLK = 512;
    int per = (N + PBLK * 4 - 1) / (PBLK * 4);
    pool_reduce<<<PBLK, 256, 0, stream>>>((const float*)H2b, batch, gsum, gmax, gcnt, N, per);
    classifier<<<NG, 128, 0, stream>>>(gsum, gmax, gcnt, Wc1, bc1, Wc2, bc2, (float*)d_out);
}

// Round 12
// 539.231 us; speedup vs baseline: 1.0083x; 1.0083x over previous
//
#include <hip/hip_runtime.h>
#include <math.h>

#define NG 64          // graphs
#define F_IN 128
#define NEG_SLOPE 0.2f

typedef __attribute__((ext_vector_type(8))) short s16x8;
typedef __attribute__((ext_vector_type(4))) float f32x4;

// ---------- helpers ----------
static __device__ __forceinline__ float elu_f(float x) { return x > 0.f ? x : expm1f(x); }
static __device__ __forceinline__ float lrelu(float x) { return x > 0.f ? x : NEG_SLOPE * x; }
static __device__ __forceinline__ unsigned enc_f32(float x) {
    unsigned u = __float_as_uint(x);
    return (u & 0x80000000u) ? ~u : (u | 0x80000000u);
}
static __device__ __forceinline__ float dec_f32(unsigned u) {
    unsigned b = (u & 0x80000000u) ? (u & 0x7fffffffu) : ~u;
    return __uint_as_float(b);
}
static __device__ __forceinline__ unsigned short bf16_rn(float x) {
    unsigned u = __float_as_uint(x);
    unsigned r = u + 0x7FFFu + ((u >> 16) & 1u);
    return (unsigned short)(r >> 16);
}
static __device__ __forceinline__ float bf16_to_f32(unsigned short h) {
    return __uint_as_float(((unsigned)h) << 16);
}

// MFMA fragment-order layout: element (row,k) of a [R][K] bf16 matrix.
static __device__ __forceinline__ size_t fragaddr(int row, int k, int K) {
    return ((size_t)(row >> 4) * (K >> 5) + (k >> 5)) * 512
         + (size_t)(((k & 31) >> 3) * 128 + (row & 15) * 8 + (k & 7));
}

static __device__ __forceinline__ void frag_store8(const float* v, unsigned short* hi,
                                                   unsigned short* lo, int row, int k0, int K) {
    unsigned short h[8], l[8];
    #pragma unroll
    for (int i = 0; i < 8; ++i) {
        h[i] = bf16_rn(v[i]);
        l[i] = bf16_rn(v[i] - bf16_to_f32(h[i]));
    }
    size_t a = fragaddr(row, k0, K);
    *(ushort4*)&hi[a]     = make_ushort4(h[0], h[1], h[2], h[3]);
    *(ushort4*)&hi[a + 4] = make_ushort4(h[4], h[5], h[6], h[7]);
    *(ushort4*)&lo[a]     = make_ushort4(l[0], l[1], l[2], l[3]);
    *(ushort4*)&lo[a + 4] = make_ushort4(l[4], l[5], l[6], l[7]);
}

// ---------- pre-pack: f32 [R][K] -> frag-order hi/lo bf16 ----------
__global__ void convert_frag(const float* __restrict__ in, unsigned short* __restrict__ hi,
                             unsigned short* __restrict__ lo, int R, int K) {
    int t = blockIdx.x * blockDim.x + threadIdx.x;
    if (t * 8 >= R * K) return;
    int row = (t * 8) / K;
    int k0 = (t * 8) % K;
    float4 v0 = *(const float4*)&in[(size_t)row * K + k0];
    float4 v1 = *(const float4*)&in[(size_t)row * K + k0 + 4];
    float v[8] = {v0.x, v0.y, v0.z, v0.w, v1.x, v1.y, v1.z, v1.w};
    frag_store8(v, hi, lo, row, k0, K);
}

// all 4 weight matrices in one launch (52 blocks)
__global__ void convert_weights(const float* __restrict__ We, const float* __restrict__ W1,
                                const float* __restrict__ W2, const float* __restrict__ W3,
                                unsigned short* WhE, unsigned short* WlE,
                                unsigned short* Wh1, unsigned short* Wl1,
                                unsigned short* Wh2, unsigned short* Wl2,
                                unsigned short* Wh3, unsigned short* Wl3) {
    int b = blockIdx.x;
    const float* in; unsigned short* hi; unsigned short* lo; int R, K, base;
    if (b < 4)       { in = We; hi = WhE; lo = WlE; R = 64;  K = 128; base = 0; }
    else if (b < 12) { in = W1; hi = Wh1; lo = Wl1; R = 256; K = 64;  base = 4; }
    else if (b < 44) { in = W2; hi = Wh2; lo = Wl2; R = 256; K = 256; base = 12; }
    else             { in = W3; hi = Wh3; lo = Wl3; R = 64;  K = 256; base = 44; }
    int t = (b - base) * 256 + threadIdx.x;
    if (t * 8 >= R * K) return;
    int row = (t * 8) / K;
    int k0 = (t * 8) % K;
    float4 v0 = *(const float4*)&in[(size_t)row * K + k0];
    float4 v1 = *(const float4*)&in[(size_t)row * K + k0 + 4];
    float v[8] = {v0.x, v0.y, v0.z, v0.w, v1.x, v1.y, v1.z, v1.w};
    frag_store8(v, hi, lo, row, k0, K);
}

// u[h][i] = sum_o W1[h*64+o][i] * a[h][o]   (layer-1 commute attention scalars)
__global__ void uvec_kernel(const float* __restrict__ W1, const float* __restrict__ a1s,
                            const float* __restrict__ a1d,
                            float* __restrict__ us, float* __restrict__ ud) {
    int h = threadIdx.x >> 6;
    int i = threadIdx.x & 63;
    float s = 0.f, d = 0.f;
    for (int o = 0; o < 64; ++o) {
        float w = W1[(h * 64 + o) * 64 + i];
        s = fmaf(w, a1s[h * 64 + o], s);
        d = fmaf(w, a1d[h * 64 + o], d);
    }
    us[h * 64 + i] = s;
    ud[h * 64 + i] = d;
}

// ---------- CSR build ----------
__global__ void hist_kernel(const int* __restrict__ ei, int* __restrict__ cnt, int E, int N) {
    int e = blockIdx.x * blockDim.x + threadIdx.x;
    int ET = E + N;
    if (e >= ET) return;
    int dst = (e < E) ? ei[E + e] : (e - E);
    atomicAdd(&cnt[dst], 1);
}

__global__ void scan1_kernel(const int* __restrict__ cnt, int* __restrict__ excl,
                             int* __restrict__ bsum, int n) {
    __shared__ int sm[256];
    int t = threadIdx.x;
    int base = blockIdx.x * 1024 + t * 4;
    int v[4];
    #pragma unroll
    for (int u = 0; u < 4; ++u) { int idx = base + u; v[u] = (idx < n) ? cnt[idx] : 0; }
    int tsum = v[0] + v[1] + v[2] + v[3];
    sm[t] = tsum;
    __syncthreads();
    for (int off = 1; off < 256; off <<= 1) {
        int y = (t >= off) ? sm[t - off] : 0;
        __syncthreads();
        sm[t] += y;
        __syncthreads();
    }
    int run = sm[t] - tsum;
    #pragma unroll
    for (int u = 0; u < 4; ++u) {
        int idx = base + u;
        if (idx < n) excl[idx] = run;
        run += v[u];
    }
    if (t == 255) bsum[blockIdx.x] = sm[255];
}

__global__ void scan2_kernel(int* __restrict__ bsum, int* __restrict__ offs, int nb, int n) {
    if (blockIdx.x == 0 && threadIdx.x == 0) {
        int run = 0;
        for (int b = 0; b < nb; ++b) { int t = bsum[b]; bsum[b] = run; run += t; }
        offs[n] = run;
    }
}

// adds block offsets AND initializes the scatter cursor (saves a memset+pass)
__global__ void scan3_kernel(int* __restrict__ offs, const int* __restrict__ bsum,
                             int* __restrict__ cur, int n) {
    int base = blockIdx.x * 1024 + threadIdx.x * 4;
    int add = bsum[blockIdx.x];
    #pragma unroll
    for (int u = 0; u < 4; ++u) {
        int idx = base + u;
        if (idx < n) { int v = offs[idx] + add; offs[idx] = v; cur[idx] = v; }
    }
}

__global__ void scatter_kernel(const int* __restrict__ ei, int* __restrict__ cur,
                               int* __restrict__ csr_src, int E, int N) {
    int e = blockIdx.x * blockDim.x + threadIdx.x;
    int ET = E + N;
    if (e >= ET) return;
    int src, dst;
    if (e < E) { src = ei[e]; dst = ei[E + e]; }
    else       { src = e - E; dst = e - E; }
    int pos = atomicAdd(&cur[dst], 1);
    csr_src[pos] = src;
}

// ---------- frag-order LDS-free split-bf16 MFMA GEMM ----------
// OUTM: 0=f32 row-major, 1=bf16 row-major, 3=frag-order split (Ohi/Olo).
template<int K, int AK, int BN, int HATT, bool SHARED, bool SLICED, bool DO_ELU, int OUTM>
__global__ __launch_bounds__(256) void gemm_frag(const unsigned short* __restrict__ Ahi,
                                                 const unsigned short* __restrict__ Alo,
                                                 const unsigned short* __restrict__ Whi,
                                                 const unsigned short* __restrict__ Wlo,
                                                 void* __restrict__ OutV,
                                                 unsigned short* __restrict__ Ohi,
                                                 unsigned short* __restrict__ Olo,
                                                 int M,
                                                 const float* __restrict__ bias,
                                                 const float* __restrict__ asrc,
                                                 const float* __restrict__ adst,
                                                 float* __restrict__ S, float* __restrict__ D,
                                                 int N) {
    constexpr int RF = (BN == 256) ? 4 : 2;
    const int t = threadIdx.x;
    const int lane = t & 63;
    const int w = t >> 6;
    const int lj = lane & 15;
    const int kg = lane >> 4;
    const int n0 = blockIdx.x * ((BN == 256) ? 64 : 128);
    const int m0 = blockIdx.y * BN;
    const int rbase = (BN == 256) ? 0 : w * 32;
    const int cbase = (BN == 256) ? w * 64 : 0;
    const int aoff = SLICED ? blockIdx.y * K : 0;
    const unsigned short* __restrict__ WhiB = SLICED ? Whi + (size_t)blockIdx.y * BN * K : Whi;
    const unsigned short* __restrict__ WloB = SLICED ? Wlo + (size_t)blockIdx.y * BN * K : Wlo;

    f32x4 acc[RF][4];
    #pragma unroll
    for (int rf = 0; rf < RF; ++rf)
        #pragma unroll
        for (int cf = 0; cf < 4; ++cf) acc[rf][cf] = (f32x4){0.f, 0.f, 0.f, 0.f};

    for (int kc = 0; kc < K; kc += 32) {
        s16x8 ah[RF], al[RF];
        #pragma unroll
        for (int rf = 0; rf < RF; ++rf) {
            size_t a = fragaddr(n0 + rbase + rf * 16 + lj, aoff + kc + kg * 8, AK);
            ah[rf] = *(const s16x8*)&Ahi[a];
            al[rf] = *(const s16x8*)&Alo[a];
        }
        #pragma unroll
        for (int cf = 0; cf < 4; ++cf) {
            int bcol = (SLICED ? 0 : m0) + cbase + cf * 16 + lj;
            size_t b = fragaddr(bcol, kc + kg * 8, K);
            s16x8 bh = *(const s16x8*)&WhiB[b];
            s16x8 bl = *(const s16x8*)&WloB[b];
            #pragma unroll
            for (int rf = 0; rf < RF; ++rf) {
                acc[rf][cf] = __builtin_amdgcn_mfma_f32_16x16x32_bf16(ah[rf], bh, acc[rf][cf], 0, 0, 0);
                acc[rf][cf] = __builtin_amdgcn_mfma_f32_16x16x32_bf16(ah[rf], bl, acc[rf][cf], 0, 0, 0);
                acc[rf][cf] = __builtin_amdgcn_mfma_f32_16x16x32_bf16(al[rf], bh, acc[rf][cf], 0, 0, 0);
            }
        }
    }

    #pragma unroll
    for (int cf = 0; cf < 4; ++cf) {
        int gcol = m0 + cbase + cf * 16 + lj;
        float bv = bias ? bias[gcol] : 0.f;
        #pragma unroll
        for (int rf = 0; rf < RF; ++rf) {
            #pragma unroll
            for (int r = 0; r < 4; ++r) {
                int gn = n0 + rbase + rf * 16 + (lane >> 4) * 4 + r;
                if (gn < N) {
                    float o = acc[rf][cf][r] + bv;
                    if (DO_ELU) o = elu_f(o);
                    if (OUTM == 0) {
                        ((float*)OutV)[(size_t)gn * M + gcol] = o;
                    } else if (OUTM == 1) {
                        ((unsigned short*)OutV)[(size_t)gn * M + gcol] = bf16_rn(o);
                    } else {
                        unsigned short hv = bf16_rn(o);
                        unsigned short lv = bf16_rn(o - bf16_to_f32(hv));
                        size_t a2 = fragaddr(gn, gcol, M);
                        Ohi[a2] = hv; Olo[a2] = lv;
                    }
                }
            }
        }
    }
    if (HATT > 0) {
        const int HS = SHARED ? HATT : 1;
        #pragma unroll
        for (int hh = 0; hh < HS; ++hh) {
            const int head = SHARED ? hh : w;
            float aw[4], dw[4], bw[4];
            #pragma unroll
            for (int c2 = 0; c2 < 4; ++c2) {
                aw[c2] = asrc[head * 64 + c2 * 16 + lj];
                dw[c2] = adst[head * 64 + c2 * 16 + lj];
                bw[c2] = bias ? bias[m0 + cbase + c2 * 16 + lj] : 0.f;
            }
            #pragma unroll
            for (int rf = 0; rf < RF; ++rf) {
                #pragma unroll
                for (int r = 0; r < 4; ++r) {
                    float sp = 0.f, dp = 0.f;
                    #pragma unroll
                    for (int c2 = 0; c2 < 4; ++c2) {
                        float vv = acc[rf][c2][r] + bw[c2];
                        sp = fmaf(vv, aw[c2], sp);
                        dp = fmaf(vv, dw[c2], dp);
                    }
                    #pragma unroll
                    for (int off = 1; off < 16; off <<= 1) {
                        sp += __shfl_xor(sp, off);
                        dp += __shfl_xor(dp, off);
                    }
                    if (lj == 0) {
                        int gn = n0 + rbase + rf * 16 + (lane >> 4) * 4 + r;
                        if (gn < N) { S[gn * HATT + head] = sp; D[gn * HATT + head] = dp; }
                    }
                }
            }
        }
    }
}

// ---------- layer-1 aggregation over bf16 emb (commuted); outputs frag-order split ----------
__global__ __launch_bounds__(256, 8) void gat_agg_x(const unsigned short* __restrict__ xb, // [N][64] bf16
                                                    const float* __restrict__ s,   // [N][4]
                                                    const float* __restrict__ d,
                                                    const int* __restrict__ offs,
                                                    const int* __restrict__ csr_src,
                                                    unsigned short* __restrict__ Gh,
                                                    unsigned short* __restrict__ Gl,
                                                    int N) {
    __shared__ float stash[4][64 * 5];
    int wv = threadIdx.x >> 6;
    int lane = threadIdx.x & 63;
    int node = (blockIdx.x * blockDim.x + threadIdx.x) >> 6;
    if (node >= N) return;
    float* st = stash[wv];
    int e0 = offs[node], e1 = offs[node + 1];
    float4 dv4 = *(const float4*)&d[node * 4];
    float dd[4] = {dv4.x, dv4.y, dv4.z, dv4.w};
    float mrun[4] = {-INFINITY, -INFINITY, -INFINITY, -INFINITY};
    float den[4] = {0.f, 0.f, 0.f, 0.f};
    float acc[4] = {0.f, 0.f, 0.f, 0.f};

    for (int base = e0; base < e1; base += 64) {
        int cnt = min(64, e1 - base);
        float ev[4] = {-INFINITY, -INFINITY, -INFINITY, -INFINITY};
        if (lane < cnt) {
            int src = csr_src[base + lane];
            float4 sv = *(const float4*)&s[src * 4];
            ev[0] = lrelu(sv.x + dd[0]); ev[1] = lrelu(sv.y + dd[1]);
            ev[2] = lrelu(sv.z + dd[2]); ev[3] = lrelu(sv.w + dd[3]);
            st[lane * 5 + 0] = ev[0]; st[lane * 5 + 1] = ev[1];
            st[lane * 5 + 2] = ev[2]; st[lane * 5 + 3] = ev[3];
            st[lane * 5 + 4] = __int_as_float(src);
        }
        #pragma unroll
        for (int h = 0; h < 4; ++h) {
            float m = ev[h];
            #pragma unroll
            for (int off = 32; off; off >>= 1) m = fmaxf(m, __shfl_xor(m, off));
            float mnew = fmaxf(mrun[h], m);
            float scale = __expf(mrun[h] - mnew);
            acc[h] *= scale; den[h] *= scale;
            mrun[h] = mnew;
        }
        int k = 0;
        for (; k + 4 <= cnt; k += 4) {
            int si[4];
            #pragma unroll
            for (int u = 0; u < 4; ++u) si[u] = __float_as_int(st[(k + u) * 5 + 4]);
            float vx[4];
            #pragma unroll
            for (int u = 0; u < 4; ++u) vx[u] = bf16_to_f32(xb[(size_t)si[u] * 64 + lane]);
            #pragma unroll
            for (int u = 0; u < 4; ++u) {
                #pragma unroll
                for (int h = 0; h < 4; ++h) {
                    float p = __expf(st[(k + u) * 5 + h] - mrun[h]);
                    den[h] += p;
                    acc[h] = fmaf(p, vx[u], acc[h]);
                }
            }
        }
        for (; k < cnt; ++k) {
            int src = __float_as_int(st[k * 5 + 4]);
            float v = bf16_to_f32(xb[(size_t)src * 64 + lane]);
            #pragma unroll
            for (int h = 0; h < 4; ++h) {
                float p = __expf(st[k * 5 + h] - mrun[h]);
                den[h] += p;
                acc[h] = fmaf(p, v, acc[h]);
            }
        }
    }
    #pragma unroll
    for (int h = 0; h < 4; ++h) {
        float v = acc[h] / (den[h] + 1e-16f);
        unsigned short hv = bf16_rn(v);
        unsigned short lv = bf16_rn(v - bf16_to_f32(hv));
        size_t a = fragaddr(node, h * 64 + lane, 256);
        Gh[a] = hv; Gl[a] = lv;
    }
}

// ---------- layer-2 aggregation: ONE wave per node, uint2 gathers (round-10 structure) ----------
template<bool FRAGOUT>
__global__ __launch_bounds__(256, 8) void gat_agg4(const unsigned short* __restrict__ hp,
                                                   const float* __restrict__ s,
                                                   const float* __restrict__ d,
                                                   const int* __restrict__ offs,
                                                   const int* __restrict__ csr_src,
                                                   const float* __restrict__ bias,
                                                   float* __restrict__ outF,
                                                   unsigned short* __restrict__ outHi,
                                                   unsigned short* __restrict__ outLo,
                                                   int N) {
    __shared__ float stash[4][64 * 5];
    int wv = threadIdx.x >> 6;
    int lane = threadIdx.x & 63;
    int node = (blockIdx.x * blockDim.x + threadIdx.x) >> 6;
    if (node >= N) return;
    float* st = stash[wv];
    int e0 = offs[node], e1 = offs[node + 1];

    float4 dv4 = *(const float4*)&d[node * 4];
    float dd[4] = {dv4.x, dv4.y, dv4.z, dv4.w};
    const int hd = lane >> 4;

    float mrun = -INFINITY;
    float acc0 = 0.f, acc1 = 0.f, acc2 = 0.f, acc3 = 0.f, den = 0.f;

    for (int base = e0; base < e1; base += 64) {
        int cnt = min(64, e1 - base);
        float ev[4] = {-INFINITY, -INFINITY, -INFINITY, -INFINITY};
        if (lane < cnt) {
            int src = csr_src[base + lane];
            float4 sv = *(const float4*)&s[src * 4];
            ev[0] = lrelu(sv.x + dd[0]); ev[1] = lrelu(sv.y + dd[1]);
            ev[2] = lrelu(sv.z + dd[2]); ev[3] = lrelu(sv.w + dd[3]);
            st[lane * 5 + 0] = ev[0]; st[lane * 5 + 1] = ev[1];
            st[lane * 5 + 2] = ev[2]; st[lane * 5 + 3] = ev[3];
            st[lane * 5 + 4] = __int_as_float(src);
        }
        float mc[4];
        #pragma unroll
        for (int h = 0; h < 4; ++h) {
            float m = ev[h];
            #pragma unroll
            for (int off = 32; off; off >>= 1) m = fmaxf(m, __shfl_xor(m, off));
            mc[h] = m;
        }
        float mch = (lane & 32) ? ((lane & 16) ? mc[3] : mc[2]) : ((lane & 16) ? mc[1] : mc[0]);
        float mnew = fmaxf(mrun, mch);
        float scale = __expf(mrun - mnew);
        acc0 *= scale; acc1 *= scale; acc2 *= scale; acc3 *= scale; den *= scale;
        mrun = mnew;

        int k = 0;
        for (; k + 4 <= cnt; k += 4) {
            float ea = st[(k + 0) * 5 + hd];
            float eb = st[(k + 1) * 5 + hd];
            float ec = st[(k + 2) * 5 + hd];
            float ed = st[(k + 3) * 5 + hd];
            int sa = __float_as_int(st[(k + 0) * 5 + 4]);
            int sb = __float_as_int(st[(k + 1) * 5 + 4]);
            int sc = __float_as_int(st[(k + 2) * 5 + 4]);
            int sd_ = __float_as_int(st[(k + 3) * 5 + 4]);
            float pa = __expf(ea - mrun);
            float pb = __expf(eb - mrun);
            float pc = __expf(ec - mrun);
            float pd = __expf(ed - mrun);
            den += (pa + pb) + (pc + pd);
            uint2 ua = *(const uint2*)&hp[(size_t)sa * 256 + lane * 4];
            uint2 ub = *(const uint2*)&hp[(size_t)sb * 256 + lane * 4];
            uint2 uc = *(const uint2*)&hp[(size_t)sc * 256 + lane * 4];
            uint2 ud = *(const uint2*)&hp[(size_t)sd_ * 256 + lane * 4];
            acc0 = fmaf(pa, __uint_as_float((ua.x & 0xffffu) << 16), acc0);
            acc1 = fmaf(pa, __uint_as_float(ua.x & 0xffff0000u), acc1);
            acc2 = fmaf(pa, __uint_as_float((ua.y & 0xffffu) << 16), acc2);
            acc3 = fmaf(pa, __uint_as_float(ua.y & 0xffff0000u), acc3);
            acc0 = fmaf(pb, __uint_as_float((ub.x & 0xffffu) << 16), acc0);
            acc1 = fmaf(pb, __uint_as_float(ub.x & 0xffff0000u), acc1);
            acc2 = fmaf(pb, __uint_as_float((ub.y & 0xffffu) << 16), acc2);
            acc3 = fmaf(pb, __uint_as_float(ub.y & 0xffff0000u), acc3);
            acc0 = fmaf(pc, __uint_as_float((uc.x & 0xffffu) << 16), acc0);
            acc1 = fmaf(pc, __uint_as_float(uc.x & 0xffff0000u), acc1);
            acc2 = fmaf(pc, __uint_as_float((uc.y & 0xffffu) << 16), acc2);
            acc3 = fmaf(pc, __uint_as_float(uc.y & 0xffff0000u), acc3);
            acc0 = fmaf(pd, __uint_as_float((ud.x & 0xffffu) << 16), acc0);
            acc1 = fmaf(pd, __uint_as_float(ud.x & 0xffff0000u), acc1);
            acc2 = fmaf(pd, __uint_as_float((ud.y & 0xffffu) << 16), acc2);
            acc3 = fmaf(pd, __uint_as_float(ud.y & 0xffff0000u), acc3);
        }
        for (; k < cnt; ++k) {
            float e = st[k * 5 + hd];
            int src = __float_as_int(st[k * 5 + 4]);
            float p = __expf(e - mrun);
            den += p;
            uint2 uv = *(const uint2*)&hp[(size_t)src * 256 + lane * 4];
            acc0 = fmaf(p, __uint_as_float((uv.x & 0xffffu) << 16), acc0);
            acc1 = fmaf(p, __uint_as_float(uv.x & 0xffff0000u), acc1);
            acc2 = fmaf(p, __uint_as_float((uv.y & 0xffffu) << 16), acc2);
            acc3 = fmaf(p, __uint_as_float(uv.y & 0xffff0000u), acc3);
        }
    }

    float inv = 1.0f / (den + 1e-16f);
    float4 bv = *(const float4*)&bias[lane * 4];
    float o0 = elu_f(acc0 * inv + bv.x);
    float o1 = elu_f(acc1 * inv + bv.y);
    float o2 = elu_f(acc2 * inv + bv.z);
    float o3 = elu_f(acc3 * inv + bv.w);
    if (FRAGOUT) {
        unsigned short h0 = bf16_rn(o0), h1 = bf16_rn(o1), h2 = bf16_rn(o2), h3 = bf16_rn(o3);
        ushort4 hq = make_ushort4(h0, h1, h2, h3);
        ushort4 lq = make_ushort4(bf16_rn(o0 - bf16_to_f32(h0)),
                                  bf16_rn(o1 - bf16_to_f32(h1)),
                                  bf16_rn(o2 - bf16_to_f32(h2)),
                                  bf16_rn(o3 - bf16_to_f32(h3)));
        size_t a = fragaddr(node, lane * 4, 256);
        *(ushort4*)&outHi[a] = hq;
        *(ushort4*)&outLo[a] = lq;
    } else {
        float4 o = make_float4(o0, o1, o2, o3);
        *(float4*)&outF[(size_t)node * 256 + lane * 4] = o;
    }
}

// ---------- layer-3 aggregation (H=1): one wave per node, bf16 table, f32 out ----------
__global__ __launch_bounds__(256, 8) void gat_agg1(const unsigned short* __restrict__ hp,
                                                   const float* __restrict__ s,
                                                   const float* __restrict__ d,
                                                   const int* __restrict__ offs,
                                                   const int* __restrict__ csr_src,
                                                   const float* __restrict__ bias,
                                                   float* __restrict__ outF, int N) {
    __shared__ float stash[4][64 * 2];
    int wv = threadIdx.x >> 6;
    int lane = threadIdx.x & 63;
    int node = (blockIdx.x * blockDim.x + threadIdx.x) >> 6;
    if (node >= N) return;
    float* st = stash[wv];
    int e0 = offs[node], e1 = offs[node + 1];
    float dd = d[node];

    float mrun = -INFINITY;
    float acc0 = 0.f, den = 0.f;

    for (int base = e0; base < e1; base += 64) {
        int cnt = min(64, e1 - base);
        float ev = -INFINITY;
        if (lane < cnt) {
            int src = csr_src[base + lane];
            ev = lrelu(s[src] + dd);
            st[lane * 2 + 0] = ev;
            st[lane * 2 + 1] = __int_as_float(src);
        }
        float m = ev;
        #pragma unroll
        for (int off = 32; off; off >>= 1) m = fmaxf(m, __shfl_xor(m, off));
        float mnew = fmaxf(mrun, m);
        float scale = __expf(mrun - mnew);
        acc0 *= scale; den *= scale;
        mrun = mnew;

        int k = 0;
        for (; k + 4 <= cnt; k += 4) {
            float ea = st[(k + 0) * 2];
            float eb = st[(k + 1) * 2];
            float ec = st[(k + 2) * 2];
            float ed = st[(k + 3) * 2];
            int sa = __float_as_int(st[(k + 0) * 2 + 1]);
            int sb = __float_as_int(st[(k + 1) * 2 + 1]);
            int sc = __float_as_int(st[(k + 2) * 2 + 1]);
            int sd_ = __float_as_int(st[(k + 3) * 2 + 1]);
            float pa = __expf(ea - mrun);
            float pb = __expf(eb - mrun);
            float pc = __expf(ec - mrun);
            float pd = __expf(ed - mrun);
            den += (pa + pb) + (pc + pd);
            float ha = bf16_to_f32(hp[(size_t)sa * 64 + lane]);
            float hb = bf16_to_f32(hp[(size_t)sb * 64 + lane]);
            float hc = bf16_to_f32(hp[(size_t)sc * 64 + lane]);
            float hdv = bf16_to_f32(hp[(size_t)sd_ * 64 + lane]);
            acc0 = fmaf(pa, ha, acc0);
            acc0 = fmaf(pb, hb, acc0);
            acc0 = fmaf(pc, hc, acc0);
            acc0 = fmaf(pd, hdv, acc0);
        }
        for (; k < cnt; ++k) {
            float e = st[k * 2];
            int src = __float_as_int(st[k * 2 + 1]);
            float p = __expf(e - mrun);
            den += p;
            acc0 = fmaf(p, bf16_to_f32(hp[(size_t)src * 64 + lane]), acc0);
        }
    }
    float inv = 1.0f / (den + 1e-16f);
    outF[(size_t)node * 64 + lane] = elu_f(acc0 * inv + bias[lane]);
}

// ---------- pooling ----------
__global__ void pool_init(float* gsum, unsigned* gmax, int* gcnt) {
    int t = blockIdx.x * blockDim.x + threadIdx.x;
    if (t < NG * 64) { gsum[t] = 0.f; gmax[t] = enc_f32(-INFINITY); }
    if (t < NG) gcnt[t] = 0;
}

__global__ void pool_reduce(const float* __restrict__ h3, const int* __restrict__ batch,
                            float* __restrict__ gsum, unsigned* __restrict__ gmax,
                            int* __restrict__ gcnt, int N, int per) {
    int w = (blockIdx.x * blockDim.x + threadIdx.x) >> 6;
    int lane = threadIdx.x & 63;
    int n0 = w * per;
    int n1 = min(N, n0 + per);
    float lsum = 0.f, lmax = -INFINITY;
    int cur = -1, cnt = 0;
    for (int n = n0; n < n1; ++n) {
        int g = batch[n];
        if (g != cur) {
            if (cur >= 0) {
                atomicAdd(&gsum[cur * 64 + lane], lsum);
                atomicMax(&gmax[cur * 64 + lane], enc_f32(lmax));
                if (lane == 0) atomicAdd(&gcnt[cur], cnt);
            }
            cur = g; lsum = 0.f; lmax = -INFINITY; cnt = 0;
        }
        float v = h3[(size_t)n * 64 + lane];
        lsum += v; lmax = fmaxf(lmax, v); cnt++;
    }
    if (cur >= 0) {
        atomicAdd(&gsum[cur * 64 + lane], lsum);
        atomicMax(&gmax[cur * 64 + lane], enc_f32(lmax));
        if (lane == 0) atomicAdd(&gcnt[cur], cnt);
    }
}

// ---------- classifier: one block per graph ----------
__global__ __launch_bounds__(128) void classifier(const float* __restrict__ gsum,
                                                  const unsigned* __restrict__ gmax,
                                                  const int* __restrict__ gcnt,
                                                  const float* __restrict__ Wc1,
                                                  const float* __restrict__ bc1,
                                                  const float* __restrict__ Wc2,
                                                  const float* __restrict__ bc2,
                                                  float* __restrict__ out) {
    __shared__ float gv[128];
    __shared__ float z1[64];
    int g = blockIdx.x, t = threadIdx.x;
    int cnt = gcnt[g];
    if (t < 64) {
        gv[t] = gsum[g * 64 + t] / fmaxf((float)cnt, 1.f);
    } else {
        float mx = dec_f32(gmax[g * 64 + (t - 64)]);
        gv[t] = (cnt > 0) ? mx : 0.f;
    }
    __syncthreads();
    if (t < 64) {
        float a = bc1[t];
        for (int k = 0; k < 128; ++k) a = fmaf(Wc1[t * 128 + k], gv[k], a);
        z1[t] = a > 0.f ? a : 0.f;
    }
    __syncthreads();
    if (t < 10) {
        float a = bc2[t];
        for (int k = 0; k < 64; ++k) a = fmaf(Wc2[t * 64 + k], z1[k], a);
        out[g * 10 + t] = a;
    }
}

// ---------- launch ----------
extern "C" void kernel_launch(void* const* d_in, const int* in_sizes, int n_in,
                              void* d_out, int out_size, void* d_ws, size_t ws_size,
                              hipStream_t stream) {
    const float* x      = (const float*)d_in[0];
    const int*   ei     = (const int*)d_in[1];
    const int*   batch  = (const int*)d_in[2];
    const float* W_emb  = (const float*)d_in[3];
    const float* b_emb  = (const float*)d_in[4];
    const float* W1     = (const float*)d_in[5];
    const float* as1    = (const float*)d_in[6];
    const float* ad1    = (const float*)d_in[7];
    const float* b1     = (const float*)d_in[8];
    const float* W2     = (const float*)d_in[9];
    const float* as2    = (const float*)d_in[10];
    const float* ad2    = (const float*)d_in[11];
    const float* b2     = (const float*)d_in[12];
    const float* W3     = (const float*)d_in[13];
    const float* as3    = (const float*)d_in[14];
    const float* ad3    = (const float*)d_in[15];
    const float* b3     = (const float*)d_in[16];
    const float* Wc1    = (const float*)d_in[17];
    const float* bc1    = (const float*)d_in[18];
    const float* Wc2    = (const float*)d_in[19];
    const float* bc2    = (const float*)d_in[20];

    const int N = in_sizes[0] / F_IN;   // 50000
    const int E = in_sizes[1] / 2;      // 800000
    const int ET = E + N;
    const int GB64 = (N + 63) / 64;     // BN=256 gemm, 64-row blocks
    const int GB128 = (N + 127) / 128;  // BN=64 gemms, 128-row blocks
    const int ROWS_FR = ((N + 255) / 256) * 256;
    const size_t FR128 = (size_t)(ROWS_FR / 16) * (128 / 32) * 512;
    const size_t FR256 = (size_t)(ROWS_FR / 16) * (256 / 32) * 512;

    size_t off = 0;
    auto alloc = [&](size_t bytes) -> void* {
        void* p = (char*)d_ws + off;
        off += (bytes + 255) & ~(size_t)255;
        return p;
    };
    unsigned short* Xh  = (unsigned short*)alloc(FR128 * 2);
    unsigned short* Xl  = (unsigned short*)alloc(FR128 * 2);
    unsigned short* Aemb= (unsigned short*)alloc((size_t)N * 64 * 2);  // emb bf16; later H3b bf16
    unsigned short* Gh  = (unsigned short*)alloc(FR256 * 2);    // G frag; later C2 frag
    unsigned short* Gl  = (unsigned short*)alloc(FR256 * 2);
    unsigned short* C1h = (unsigned short*)alloc(FR256 * 2);
    unsigned short* C1l = (unsigned short*)alloc(FR256 * 2);
    unsigned short* H2b = (unsigned short*)alloc((size_t)N * 256 * 2); // h2 bf16; later h3 f32
    unsigned short* WhE = (unsigned short*)alloc(64 * 128 * 2);
    unsigned short* WlE = (unsigned short*)alloc(64 * 128 * 2);
    unsigned short* Wh1 = (unsigned short*)alloc(256 * 64 * 2);
    unsigned short* Wl1 = (unsigned short*)alloc(256 * 64 * 2);
    unsigned short* Wh2 = (unsigned short*)alloc(256 * 256 * 2);
    unsigned short* Wl2 = (unsigned short*)alloc(256 * 256 * 2);
    unsigned short* Wh3 = (unsigned short*)alloc(64 * 256 * 2);
    unsigned short* Wl3 = (unsigned short*)alloc(64 * 256 * 2);
    float*    us1     = (float*)alloc(4 * 64 * 4);
    float*    ud1     = (float*)alloc(4 * 64 * 4);
    float*    S       = (float*)alloc((size_t)N * 4 * 4);
    float*    D       = (float*)alloc((size_t)N * 4 * 4);
    int*      offs    = (int*)alloc((size_t)(N + 1) * 4);
    int*      cnt     = (int*)alloc((size_t)N * 4);
    int*      bsum    = (int*)alloc(64 * 4);
    int*      csr_src = (int*)alloc((size_t)ET * 4);
    float*    gsum    = (float*)alloc(NG * 64 * 4);
    unsigned* gmax    = (unsigned*)alloc(NG * 64 * 4);
    int*      gcnt    = (int*)alloc(NG * 4);
    (void)ws_size; (void)n_in; (void)out_size;

    const int SCB = (N + 1023) / 1024;

    // pre-pack to fragment order
    convert_frag<<<(N * 128 / 8 + 255) / 256, 256, 0, stream>>>(x, Xh, Xl, N, 128);
    convert_weights<<<52, 256, 0, stream>>>(W_emb, W1, W2, W3, WhE, WlE, Wh1, Wl1,
                                            Wh2, Wl2, Wh3, Wl3);
    uvec_kernel<<<1, 256, 0, stream>>>(W1, as1, ad1, us1, ud1);

    // CSR build
    hipMemsetAsync(cnt, 0, (size_t)N * 4, stream);
    hist_kernel<<<(ET + 255) / 256, 256, 0, stream>>>(ei, cnt, E, N);
    scan1_kernel<<<SCB, 256, 0, stream>>>(cnt, offs, bsum, N);
    scan2_kernel<<<1, 64, 0, stream>>>(bsum, offs, SCB, N);
    scan3_kernel<<<SCB, 256, 0, stream>>>(offs, bsum, cnt, N);
    scatter_kernel<<<(ET + 255) / 256, 256, 0, stream>>>(ei, cnt, csr_src, E, N);

    const int NWV = (N * 64 + 255) / 256;          // 1 wave/node

    // embedding: Aemb(bf16) = x@W_embT + b_emb, fused s1,d1 via commute u-vectors
    gemm_frag<128, 128, 64, 4, true, false, false, 1><<<dim3(GB128, 1), 256, 0, stream>>>(
        Xh, Xl, WhE, WlE, Aemb, nullptr, nullptr, 64, b_emb, us1, ud1, S, D, N);
    // layer-1 commuted aggregation (gathers bf16 emb; outputs frag G)
    gat_agg_x<<<NWV, 256, 0, stream>>>(Aemb, S, D, offs, csr_src, Gh, Gl, N);
    // per-head transform: C1 = frag(elu(G_h @ W1_hT + b1))
    gemm_frag<64, 256, 64, 0, false, true, true, 3><<<dim3(GB128, 4), 256, 0, stream>>>(
        Gh, Gl, Wh1, Wl1, nullptr, C1h, C1l, 256, b1, nullptr, nullptr, nullptr, nullptr, N);
    // layer 2: H2b(bf16) = C1@W2T, fused s2,d2
    gemm_frag<256, 256, 256, 4, false, false, false, 1><<<dim3(GB64, 1), 256, 0, stream>>>(
        C1h, C1l, Wh2, Wl2, H2b, nullptr, nullptr, 256, nullptr, as2, ad2, S, D, N);
    // layer-2 aggregation: 1 wave/node, uint2 gathers, frag-order output
    gat_agg4<true><<<NWV, 256, 0, stream>>>(H2b, S, D, offs, csr_src, b2,
                                            nullptr, Gh, Gl, N);
    // layer 3: H3b(bf16, in Aemb buffer) = C2@W3T, fused s3,d3
    gemm_frag<256, 256, 64, 1, true, false, false, 1><<<dim3(GB128, 1), 256, 0, stream>>>(
        Gh, Gl, Wh3, Wl3, Aemb, nullptr, nullptr, 64, nullptr, as3, ad3, S, D, N);
    gat_agg1<<<NWV, 256, 0, stream>>>(Aemb, S, D, offs, csr_src, b3, (float*)H2b, N);

    // pooling + classifier (h3 f32 in H2b buffer)
    pool_init<<<16, 256, 0, stream>>>(gsum, gmax, gcnt);
    const int PBLK = 512;
    int per = (N + PBLK * 4 - 1) / (PBLK * 4);
    pool_reduce<<<PBLK, 256, 0, stream>>>((const float*)H2b, batch, gsum, gmax, gcnt, N, per);
    classifier<<<NG, 128, 0, stream>>>(gsum, gmax, gcnt, Wc1, bc1, Wc2, bc2, (float*)d_out);
}